// Round 4
// baseline (275.914 us; speedup 1.0000x reference)
//
#include <hip/hip_runtime.h>
#include <stdint.h>

#define NB 4
#define NWS 64
#define TT 65536
#define TCC 1024
#define CEE 128
#define WW 16

#define INV2PI 0.15915494309189535f

// ws layout (float offsets)
#define OFF_FILM  0
#define OFF_W0S   (OFF_FILM + NB*256*TCC)     // 1048576
#define OFF_B0S   (OFF_W0S + 1024)
#define OFF_B1S   (OFF_B0S + 1024)
#define OFF_W2S   (OFF_B1S + 1024)
#define OFF_B2S   (OFF_W2S + 1024)
#define OFF_MIX   (OFF_B2S + 64)
#define OFF_AFRAG (OFF_MIX + 64)              // 16384 f16 = 8192 floats, even offset

typedef _Float16 half4_t __attribute__((ext_vector_type(4)));
typedef float f32x4_t __attribute__((ext_vector_type(4)));

__device__ __forceinline__ float sinrev(float r) {
  // sin(2*pi*r); weights/biases pre-scaled by 1/2pi
#if __has_builtin(__builtin_amdgcn_fractf) && __has_builtin(__builtin_amdgcn_sinf)
  return __builtin_amdgcn_sinf(__builtin_amdgcn_fractf(r));
#else
  float fr = r - floorf(r);
  return __sinf(fr * 6.283185307179586f);
#endif
}

// ---------------- prep: pre-scale shaper weights; pack W1 into A-frags -----
__global__ __launch_bounds__(256) void k_prep(
    const float* __restrict__ iscale,
    const float* __restrict__ w0, const float* __restrict__ b0,
    const float* __restrict__ w1, const float* __restrict__ b1,
    const float* __restrict__ w2, const float* __restrict__ b2,
    const float* __restrict__ mixw,
    float* __restrict__ ws) {
  int i = blockIdx.x * 256 + threadIdx.x;
  if (i < NWS * WW) {
    int n = i / WW;
    ws[OFF_W0S + i] = w0[i] * iscale[n] * INV2PI;
    ws[OFF_B0S + i] = b0[i] * INV2PI;
    ws[OFF_B1S + i] = b1[i] * INV2PI;
    ws[OFF_W2S + i] = w2[i] * INV2PI;
  }
  if (i < NWS) {
    ws[OFF_B2S + i] = b2[i] * INV2PI;
    ws[OFF_MIX + i] = mixw[i];
  }
  if (i < NWS * 64) {
    // A-fragment for v_mfma_f32_16x16x16_f16: lane l holds A[m][k],
    // m = l&15, k = (l>>4)*4 + j   (A = W1[n][m][k] / 2pi, f16)
    int n = i >> 6, l = i & 63;
    int m = l & 15, k0 = (l >> 4) * 4;
    union { uint2 u; half4_t h; } cv;
    #pragma unroll
    for (int j = 0; j < 4; ++j)
      cv.h[j] = (_Float16)(w1[(n * 16 + m) * 16 + k0 + j] * INV2PI);
    ((uint2*)(ws + OFF_AFRAG))[i] = cv.u;
  }
}

// ---------------- kernel 1: TimeDistributedMLP -> film [B,256,TC] fp32 -----
// block 256 = (o:128) x (h:2); 8 columns/block; weights staged in LDS
// (pad-65 rows: reads lane=o consecutive -> 2-way bank alias = free)
#define MCOLS 8
__global__ __launch_bounds__(256) void k_mlp(
    const float* __restrict__ ce,
    const float* __restrict__ w0, const float* __restrict__ b0,
    const float* __restrict__ g0, const float* __restrict__ e0,
    const float* __restrict__ w1, const float* __restrict__ b1,
    const float* __restrict__ g1, const float* __restrict__ e1,
    const float* __restrict__ w2, const float* __restrict__ b2,
    const float* __restrict__ g2, const float* __restrict__ e2,
    const float* __restrict__ w3, const float* __restrict__ b3,
    float* __restrict__ film) {
  const int tid = threadIdx.x;
  const int o = tid & 127;
  const int h = tid >> 7;            // column half: cols h*4 .. h*4+3
  const int wvid = tid >> 6;         // wave id 0..3
  const int bx = blockIdx.x;
  const int b = bx >> 7;
  const int tc0 = (bx & 127) * MCOLS;

  __shared__ float wlds[128 * 65];                 // one c-half of a layer
  __shared__ __align__(16) float xa[CEE * MCOLS];
  __shared__ __align__(16) float xb[CEE * MCOLS];
  __shared__ float red[4][2][4];
  __shared__ float stat[2][MCOLS];

  if (tid < 128) {
    const float* src = ce + ((size_t)(b * CEE + tid)) * TCC + tc0;
    *(float4*)(xa + tid * MCOLS) = *(const float4*)src;
    *(float4*)(xa + tid * MCOLS + 4) = *(const float4*)(src + 4);
  }

  float* xin = xa; float* xout = xb;
  const float* Wp[3] = {w0, w1, w2};
  const float* Bp[3] = {b0, b1, b2};
  const float* Gp[3] = {g0, g1, g2};
  const float* Ep[3] = {e0, e1, e2};

  for (int L = 0; L < 3; ++L) {
    float acc[4];
    float bias = Bp[L][o];
    #pragma unroll
    for (int cc = 0; cc < 4; ++cc) acc[cc] = bias;

    for (int half = 0; half < 2; ++half) {
      __syncthreads();
      // stage W[:, half*64 .. half*64+63] into LDS (coalesced)
      const float* wsrc = Wp[L] + half * 64;
      for (int i = tid; i < 4096; i += 256) {
        int oo = i >> 5, cc2 = (i & 31) * 2;
        float2 wv = *(const float2*)(wsrc + (size_t)oo * CEE + cc2);
        wlds[oo * 65 + cc2] = wv.x;
        wlds[oo * 65 + cc2 + 1] = wv.y;
      }
      __syncthreads();
      const float* xcol = xin + half * 64 * MCOLS + h * 4;
      const float* wr = wlds + o * 65;
      #pragma unroll 8
      for (int c = 0; c < 64; ++c) {
        float w = wr[c];
        float4 xv = *(const float4*)(xcol + c * MCOLS);
        acc[0] = fmaf(w, xv.x, acc[0]); acc[1] = fmaf(w, xv.y, acc[1]);
        acc[2] = fmaf(w, xv.z, acc[2]); acc[3] = fmaf(w, xv.w, acc[3]);
      }
    }

    // LayerNorm over the 128 channels for each of this thread's 4 columns
    float s[4], q[4];
    #pragma unroll
    for (int cc = 0; cc < 4; ++cc) { s[cc] = acc[cc]; q[cc] = acc[cc] * acc[cc]; }
    #pragma unroll
    for (int m = 1; m < 64; m <<= 1) {
      #pragma unroll
      for (int cc = 0; cc < 4; ++cc) {
        s[cc] += __shfl_xor(s[cc], m, 64);
        q[cc] += __shfl_xor(q[cc], m, 64);
      }
    }
    if ((tid & 63) == 0) {
      #pragma unroll
      for (int cc = 0; cc < 4; ++cc) { red[wvid][0][cc] = s[cc]; red[wvid][1][cc] = q[cc]; }
    }
    __syncthreads();
    if (tid < MCOLS) {
      int hh = tid >> 2, cc = tid & 3;
      float st = red[2 * hh][0][cc] + red[2 * hh + 1][0][cc];
      float qt = red[2 * hh][1][cc] + red[2 * hh + 1][1][cc];
      float mu = st * (1.0f / CEE);
      float var = qt * (1.0f / CEE) - mu * mu;
      stat[0][tid] = mu;
      stat[1][tid] = rsqrtf(var + 1e-5f);
    }
    __syncthreads();
    float g = Gp[L][o], e = Ep[L][o];
    #pragma unroll
    for (int cc = 0; cc < 4; ++cc) {
      int col = h * 4 + cc;
      float v = (acc[cc] - stat[0][col]) * stat[1][col] * g + e;
      v = fmaxf(v, 0.01f * v);      // LeakyReLU
      xout[o * MCOLS + col] = v;
    }
    float* tmp = xin; xin = xout; xout = tmp;
  }

  // final layer CE -> 256: two row-halves x two c-halves (staged quarters)
  for (int hh = 0; hh < 2; ++hh) {
    float acc[4];
    float bias = b3[hh * 128 + o];
    #pragma unroll
    for (int cc = 0; cc < 4; ++cc) acc[cc] = bias;
    for (int half = 0; half < 2; ++half) {
      __syncthreads();
      const float* wsrc = w3 + (size_t)hh * 128 * CEE + half * 64;
      for (int i = tid; i < 4096; i += 256) {
        int oo = i >> 5, cc2 = (i & 31) * 2;
        float2 wv = *(const float2*)(wsrc + (size_t)oo * CEE + cc2);
        wlds[oo * 65 + cc2] = wv.x;
        wlds[oo * 65 + cc2 + 1] = wv.y;
      }
      __syncthreads();
      const float* xcol = xin + half * 64 * MCOLS + h * 4;
      const float* wr = wlds + o * 65;
      #pragma unroll 8
      for (int c = 0; c < 64; ++c) {
        float w = wr[c];
        float4 xv = *(const float4*)(xcol + c * MCOLS);
        acc[0] = fmaf(w, xv.x, acc[0]); acc[1] = fmaf(w, xv.y, acc[1]);
        acc[2] = fmaf(w, xv.z, acc[2]); acc[3] = fmaf(w, xv.w, acc[3]);
      }
    }
    float* dst = film + ((size_t)(b * 256 + hh * 128 + o)) * TCC + tc0 + h * 4;
    *(float4*)dst = *(float4*)acc;
  }
}

// ---------------- kernel 2: FiLM + MFMA waveshaper + mix + x4 + store ------
// grid: 256 tiles x 4 batches; block 256 threads (4 waves x 64 t each)
__global__ __launch_bounds__(256) void k_shape(
    const float* __restrict__ exciter,
    const float* __restrict__ ws,
    const float* __restrict__ mixb,
    float* __restrict__ out) {
  const int tid = threadIdx.x;
  const int lane = tid & 63;
  const int wv = tid >> 6;
  const int bx = blockIdx.x;
  const int blk = bx & 255;
  const int b = bx >> 8;
  const int t0_blk = blk * 256;
  const int tcbase = blk * 4 - 1;

  __shared__ float FL[4 * 64 * 6];
  __shared__ __align__(16) float W0s[NWS * 16], B0s[NWS * 16], B1s[NWS * 16], W2s[NWS * 16];
  __shared__ float B2s[NWS], MWs[NWS];

  for (int i = tid; i < 1024; i += 256) {
    W0s[i] = ws[OFF_W0S + i];
    B0s[i] = ws[OFF_B0S + i];
    B1s[i] = ws[OFF_B1S + i];
    W2s[i] = ws[OFF_W2S + i];
  }
  if (tid < 64) { B2s[tid] = ws[OFF_B2S + tid]; MWs[tid] = ws[OFF_MIX + tid]; }
  for (int i = tid; i < 1536; i += 256) {
    int p = i / 384, r = i - p * 384, n = r / 6, j = r - n * 6;
    int tc = tcbase + j; tc = tc < 0 ? 0 : (tc > 1023 ? 1023 : tc);
    FL[i] = ws[OFF_FILM + ((size_t)(b * 256 + p * 64 + n)) * TCC + tc];
  }
  __syncthreads();

  const int t_own = t0_blk + wv * 64 + lane;
  float pos = ((float)t_own + 0.5f) * (1.0f / 64.0f) - 0.5f;
  pos = fminf(fmaxf(pos, 0.0f), 1023.0f);
  float fi = floorf(pos);
  int i0 = (int)fi;
  float frac = pos - fi;
  int i1 = i0 + 1; if (i1 > 1023) i1 = 1023;
  const int j0 = i0 - tcbase, j1 = i1 - tcbase;

  const int quad = lane >> 4;
  const int l16 = lane & 15;

  float acc = 0.0f;
  const float* excp = exciter + ((size_t)b * NWS) * TT + t_own;
  const uint2* afr = (const uint2*)(ws + OFF_AFRAG);

  float ev = excp[0];
  uint2 af = afr[lane];
  for (int n = 0; n < NWS; ++n) {
    float ev_n = 0.f; uint2 af_n = af;
    if (n < NWS - 1) {
      ev_n = excp[(size_t)(n + 1) * TT];
      af_n = afr[(n + 1) * 64 + lane];
    }
    const float* fgi = FL + (0 * 64 + n) * 6;
    const float* fbi = FL + (1 * 64 + n) * 6;
    const float* fgn = FL + (2 * 64 + n) * 6;
    const float* fbn = FL + (3 * 64 + n) * 6;
    float gi0 = fgi[j0], gi = fmaf(fgi[j1] - gi0, frac, gi0);
    float bi0 = fbi[j0], bi = fmaf(fbi[j1] - bi0, frac, bi0);
    float gn0 = fgn[j0], gn = fmaf(fgn[j1] - gn0, frac, gn0);
    float bn0 = fbn[j0], bn = fmaf(fbn[j1] - bn0, frac, bn0);
    float x = fmaf(gi, ev, bi);

    f32x4_t w0f = *(const f32x4_t*)(W0s + n * 16 + quad * 4);
    f32x4_t b0f = *(const f32x4_t*)(B0s + n * 16 + quad * 4);
    f32x4_t b1f = *(const f32x4_t*)(B1s + n * 16 + quad * 4);
    f32x4_t w2f = *(const f32x4_t*)(W2s + n * 16 + quad * 4);
    half4_t a;
    { union { uint2 u; half4_t h; } cv; cv.u = af; a = cv.h; }
    float b2v = B2s[n], mwv = MWs[n];

    #pragma unroll
    for (int g = 0; g < 4; ++g) {
      float xg = __shfl(x, g * 16 + l16, 64);
      half4_t bfrag;
      #pragma unroll
      for (int k = 0; k < 4; ++k)
        bfrag[k] = (_Float16)sinrev(fmaf(xg, w0f[k], b0f[k]));
      f32x4_t c;
      c[0] = b1f[0]; c[1] = b1f[1]; c[2] = b1f[2]; c[3] = b1f[3];
      f32x4_t d = __builtin_amdgcn_mfma_f32_16x16x16f16(a, bfrag, c, 0, 0, 0);
      float y = 0.0f;
      #pragma unroll
      for (int r = 0; r < 4; ++r) y = fmaf(sinrev(d[r]), w2f[r], y);
      y += __shfl_xor(y, 16, 64);
      y += __shfl_xor(y, 32, 64);
      float z = sinrev(y + b2v);
      float contrib = fmaf(mwv, fmaf(gn, z, bn), acc);
      acc = (quad == g) ? contrib : acc;   // only own-t lanes accumulate
    }
    ev = ev_n; af = af_n;
  }
  float v = acc + mixb[0];
  float4 o4 = {v, v, v, v};
  *(float4*)(out + (size_t)(b * TT + t_own) * 4) = o4;
}

extern "C" void kernel_launch(void* const* d_in, const int* in_sizes, int n_in,
                              void* d_out, int out_size, void* d_ws, size_t ws_size,
                              hipStream_t stream) {
  const float* exciter = (const float*)d_in[0];
  const float* ce      = (const float*)d_in[1];
  const float* w0  = (const float*)d_in[2];
  const float* b0  = (const float*)d_in[3];
  const float* g0  = (const float*)d_in[4];
  const float* e0  = (const float*)d_in[5];
  const float* w1  = (const float*)d_in[6];
  const float* b1  = (const float*)d_in[7];
  const float* g1  = (const float*)d_in[8];
  const float* e1  = (const float*)d_in[9];
  const float* w2  = (const float*)d_in[10];
  const float* b2  = (const float*)d_in[11];
  const float* g2  = (const float*)d_in[12];
  const float* e2  = (const float*)d_in[13];
  const float* w3  = (const float*)d_in[14];
  const float* b3  = (const float*)d_in[15];
  const float* iscale = (const float*)d_in[16];
  const float* sw0 = (const float*)d_in[17];
  const float* sb0 = (const float*)d_in[18];
  const float* sw1 = (const float*)d_in[19];
  const float* sb1 = (const float*)d_in[20];
  const float* sw2 = (const float*)d_in[21];
  const float* sb2 = (const float*)d_in[22];
  const float* mixw = (const float*)d_in[23];
  const float* mixb = (const float*)d_in[24];

  float* ws = (float*)d_ws;

  hipLaunchKernelGGL(k_prep, dim3(16), dim3(256), 0, stream,
                     iscale, sw0, sb0, sw1, sb1, sw2, sb2, mixw, ws);
  hipLaunchKernelGGL(k_mlp, dim3(512), dim3(256), 0, stream,
                     ce, w0, b0, g0, e0, w1, b1, g1, e1, w2, b2, g2, e2, w3, b3,
                     ws + OFF_FILM);
  hipLaunchKernelGGL(k_shape, dim3(1024), dim3(256), 0, stream,
                     exciter, ws, mixb, (float*)d_out);
}

// Round 5
// 261.317 us; speedup vs baseline: 1.0559x; 1.0559x over previous
//
#include <hip/hip_runtime.h>
#include <stdint.h>

#define NB 4
#define NWS 64
#define TT 65536
#define TCC 1024
#define CEE 128
#define WW 16

#define INV2PI 0.15915494309189535f

// ws layout (float offsets)
#define OFF_FILM  0
#define OFF_W0S   (OFF_FILM + NB*256*TCC)     // 1048576
#define OFF_B0S   (OFF_W0S + 1024)
#define OFF_B1S   (OFF_B0S + 1024)
#define OFF_B2S   (OFF_B1S + 1024)
#define OFF_MIX   (OFF_B2S + 64)
#define OFF_AFRAG (OFF_MIX + 64)              // W1 A-frags: 4096 uint2 = 8192 words
#define OFF_A2F   (OFF_AFRAG + 8192)          // w2 A-frags: 4096 uint2 = 8192 words
#define OFF_PART  (OFF_A2F + 8192)            // 2*NB*TT floats

typedef _Float16 half4_t __attribute__((ext_vector_type(4)));
typedef float f32x4_t __attribute__((ext_vector_type(4)));

__device__ __forceinline__ float sinrev(float r) {
  // sin(2*pi*r); weights/biases pre-scaled by 1/2pi
#if __has_builtin(__builtin_amdgcn_fractf) && __has_builtin(__builtin_amdgcn_sinf)
  return __builtin_amdgcn_sinf(__builtin_amdgcn_fractf(r));
#else
  float fr = r - floorf(r);
  return __sinf(fr * 6.283185307179586f);
#endif
}

// ---------------- prep: pre-scale shaper weights; pack W1/w2 A-frags -------
__global__ __launch_bounds__(256) void k_prep(
    const float* __restrict__ iscale,
    const float* __restrict__ w0, const float* __restrict__ b0,
    const float* __restrict__ w1, const float* __restrict__ b1,
    const float* __restrict__ w2, const float* __restrict__ b2,
    const float* __restrict__ mixw,
    float* __restrict__ ws) {
  int i = blockIdx.x * 256 + threadIdx.x;
  if (i < NWS * WW) {
    int n = i / WW;
    ws[OFF_W0S + i] = w0[i] * iscale[n] * INV2PI;
    ws[OFF_B0S + i] = b0[i] * INV2PI;
    ws[OFF_B1S + i] = b1[i] * INV2PI;
  }
  if (i < NWS) {
    ws[OFF_B2S + i] = b2[i] * INV2PI;
    ws[OFF_MIX + i] = mixw[i];
  }
  if (i < NWS * 64) {
    int n = i >> 6, l = i & 63;
    int m = l & 15, k0 = (l >> 4) * 4;
    // A1-frag: lane l holds W1[n][m][k0+j] / 2pi  (m = l&15, k = quad*4+j)
    union { uint2 u; half4_t h; } cv;
    #pragma unroll
    for (int j = 0; j < 4; ++j)
      cv.h[j] = (_Float16)(w1[(n * 16 + m) * 16 + k0 + j] * INV2PI);
    ((uint2*)(ws + OFF_AFRAG))[i] = cv.u;
    // A2-frag: A2[m][k] = w2[n][k] / 2pi  (row-independent broadcast)
    union { uint2 u; half4_t h; } c2;
    #pragma unroll
    for (int j = 0; j < 4; ++j)
      c2.h[j] = (_Float16)(w2[n * 16 + k0 + j] * INV2PI);
    ((uint2*)(ws + OFF_A2F))[i] = c2.u;
  }
}

// ---------------- kernel 1: TimeDistributedMLP -> film [B,256,TC] fp32 -----
#define MCOLS 8
__global__ __launch_bounds__(256) void k_mlp(
    const float* __restrict__ ce,
    const float* __restrict__ w0, const float* __restrict__ b0,
    const float* __restrict__ g0, const float* __restrict__ e0,
    const float* __restrict__ w1, const float* __restrict__ b1,
    const float* __restrict__ g1, const float* __restrict__ e1,
    const float* __restrict__ w2, const float* __restrict__ b2,
    const float* __restrict__ g2, const float* __restrict__ e2,
    const float* __restrict__ w3, const float* __restrict__ b3,
    float* __restrict__ film) {
  const int tid = threadIdx.x;
  const int o = tid & 127;
  const int h = tid >> 7;
  const int wvid = tid >> 6;
  const int bx = blockIdx.x;
  const int b = bx >> 7;
  const int tc0 = (bx & 127) * MCOLS;

  __shared__ float wlds[128 * 65];
  __shared__ __align__(16) float xa[CEE * MCOLS];
  __shared__ __align__(16) float xb[CEE * MCOLS];
  __shared__ float red[4][2][4];
  __shared__ float stat[2][MCOLS];

  if (tid < 128) {
    const float* src = ce + ((size_t)(b * CEE + tid)) * TCC + tc0;
    *(float4*)(xa + tid * MCOLS) = *(const float4*)src;
    *(float4*)(xa + tid * MCOLS + 4) = *(const float4*)(src + 4);
  }

  float* xin = xa; float* xout = xb;
  const float* Wp[3] = {w0, w1, w2};
  const float* Bp[3] = {b0, b1, b2};
  const float* Gp[3] = {g0, g1, g2};
  const float* Ep[3] = {e0, e1, e2};

  for (int L = 0; L < 3; ++L) {
    float acc[4];
    float bias = Bp[L][o];
    #pragma unroll
    for (int cc = 0; cc < 4; ++cc) acc[cc] = bias;

    for (int half = 0; half < 2; ++half) {
      __syncthreads();
      const float* wsrc = Wp[L] + half * 64;
      for (int i = tid; i < 4096; i += 256) {
        int oo = i >> 5, cc2 = (i & 31) * 2;
        float2 wv = *(const float2*)(wsrc + (size_t)oo * CEE + cc2);
        wlds[oo * 65 + cc2] = wv.x;
        wlds[oo * 65 + cc2 + 1] = wv.y;
      }
      __syncthreads();
      const float* xcol = xin + half * 64 * MCOLS + h * 4;
      const float* wr = wlds + o * 65;
      #pragma unroll 8
      for (int c = 0; c < 64; ++c) {
        float w = wr[c];
        float4 xv = *(const float4*)(xcol + c * MCOLS);
        acc[0] = fmaf(w, xv.x, acc[0]); acc[1] = fmaf(w, xv.y, acc[1]);
        acc[2] = fmaf(w, xv.z, acc[2]); acc[3] = fmaf(w, xv.w, acc[3]);
      }
    }

    float s[4], q[4];
    #pragma unroll
    for (int cc = 0; cc < 4; ++cc) { s[cc] = acc[cc]; q[cc] = acc[cc] * acc[cc]; }
    #pragma unroll
    for (int m = 1; m < 64; m <<= 1) {
      #pragma unroll
      for (int cc = 0; cc < 4; ++cc) {
        s[cc] += __shfl_xor(s[cc], m, 64);
        q[cc] += __shfl_xor(q[cc], m, 64);
      }
    }
    if ((tid & 63) == 0) {
      #pragma unroll
      for (int cc = 0; cc < 4; ++cc) { red[wvid][0][cc] = s[cc]; red[wvid][1][cc] = q[cc]; }
    }
    __syncthreads();
    if (tid < MCOLS) {
      int hh = tid >> 2, cc = tid & 3;
      float st = red[2 * hh][0][cc] + red[2 * hh + 1][0][cc];
      float qt = red[2 * hh][1][cc] + red[2 * hh + 1][1][cc];
      float mu = st * (1.0f / CEE);
      float var = qt * (1.0f / CEE) - mu * mu;
      stat[0][tid] = mu;
      stat[1][tid] = rsqrtf(var + 1e-5f);
    }
    __syncthreads();
    float g = Gp[L][o], e = Ep[L][o];
    #pragma unroll
    for (int cc = 0; cc < 4; ++cc) {
      int col = h * 4 + cc;
      float v = (acc[cc] - stat[0][col]) * stat[1][col] * g + e;
      v = fmaxf(v, 0.01f * v);
      xout[o * MCOLS + col] = v;
    }
    float* tmp = xin; xin = xout; xout = tmp;
  }

  for (int hh = 0; hh < 2; ++hh) {
    float acc[4];
    float bias = b3[hh * 128 + o];
    #pragma unroll
    for (int cc = 0; cc < 4; ++cc) acc[cc] = bias;
    for (int half = 0; half < 2; ++half) {
      __syncthreads();
      const float* wsrc = w3 + (size_t)hh * 128 * CEE + half * 64;
      for (int i = tid; i < 4096; i += 256) {
        int oo = i >> 5, cc2 = (i & 31) * 2;
        float2 wv = *(const float2*)(wsrc + (size_t)oo * CEE + cc2);
        wlds[oo * 65 + cc2] = wv.x;
        wlds[oo * 65 + cc2 + 1] = wv.y;
      }
      __syncthreads();
      const float* xcol = xin + half * 64 * MCOLS + h * 4;
      const float* wr = wlds + o * 65;
      #pragma unroll 8
      for (int c = 0; c < 64; ++c) {
        float w = wr[c];
        float4 xv = *(const float4*)(xcol + c * MCOLS);
        acc[0] = fmaf(w, xv.x, acc[0]); acc[1] = fmaf(w, xv.y, acc[1]);
        acc[2] = fmaf(w, xv.z, acc[2]); acc[3] = fmaf(w, xv.w, acc[3]);
      }
    }
    float* dst = film + ((size_t)(b * 256 + hh * 128 + o)) * TCC + tc0 + h * 4;
    *(float4*)dst = *(float4*)acc;
  }
}

// ---------------- kernel 2: FiLM + dual-MFMA waveshaper -> partials --------
// grid: 256 t-tiles x 4 batches x 2 channel-halves; block 256 (4 waves x 64 t)
__global__ __launch_bounds__(256, 8) void k_shape(
    const float* __restrict__ exciter,
    const float* __restrict__ ws,
    float* __restrict__ part) {
  const int tid = threadIdx.x;
  const int lane = tid & 63;
  const int wv = tid >> 6;
  const int bx = blockIdx.x;
  const int blk = bx & 255;
  const int b = (bx >> 8) & 3;
  const int half = bx >> 10;
  const int n0 = half * 32;
  const int t0_blk = blk * 256;
  const int tcbase = blk * 4 - 1;

  __shared__ float FL[32 * 24];                    // [n][param][6]
  __shared__ __align__(16) float W0s[32 * 16], B0s[32 * 16], B1s[32 * 16];
  __shared__ float BMs[32 * 2];                    // (b2, mw) interleaved

  for (int i = tid; i < 512; i += 256) {
    W0s[i] = ws[OFF_W0S + n0 * 16 + i];
    B0s[i] = ws[OFF_B0S + n0 * 16 + i];
    B1s[i] = ws[OFF_B1S + n0 * 16 + i];
  }
  if (tid < 64) {
    int n = tid >> 1;
    BMs[tid] = (tid & 1) ? ws[OFF_MIX + n0 + n] : ws[OFF_B2S + n0 + n];
  }
  for (int i = tid; i < 768; i += 256) {
    int n = i / 24, r = i - n * 24, p = r / 6, j = r - p * 6;
    int tc = tcbase + j; tc = tc < 0 ? 0 : (tc > 1023 ? 1023 : tc);
    FL[i] = ws[OFF_FILM + ((size_t)(b * 256 + p * 64 + n0 + n)) * TCC + tc];
  }
  __syncthreads();

  const int t_own = t0_blk + wv * 64 + lane;
  float pos = ((float)t_own + 0.5f) * (1.0f / 64.0f) - 0.5f;
  pos = fminf(fmaxf(pos, 0.0f), 1023.0f);
  float fi = floorf(pos);
  int i0 = (int)fi;
  const float frac = pos - fi;
  const int j0 = i0 - tcbase;        // j1 == j0+1 always (window clamp-duped)

  const int quad = lane >> 4;
  const int l16 = lane & 15;

  float acc = 0.0f;
  const float* excp = exciter + ((size_t)(b * NWS + n0)) * TT + t_own;
  const uint2* af1p = (const uint2*)(ws + OFF_AFRAG) + (size_t)n0 * 64 + lane;
  const uint2* af2p = (const uint2*)(ws + OFF_A2F) + (size_t)n0 * 64 + lane;

  float ev = excp[0];
  uint2 af1 = af1p[0];
  uint2 af2 = af2p[0];
  for (int n = 0; n < 32; ++n) {
    float ev_n = 0.f; uint2 af1_n = af1, af2_n = af2;
    if (n < 31) {
      ev_n = excp[(size_t)(n + 1) * TT];
      af1_n = af1p[(n + 1) * 64];
      af2_n = af2p[(n + 1) * 64];
    }
    const float* fb = FL + n * 24;
    const float* pgi = fb + j0;
    const float* pbi = fb + 6 + j0;
    const float* pgn = fb + 12 + j0;
    const float* pbn = fb + 18 + j0;
    float gi0 = pgi[0], gi = fmaf(pgi[1] - gi0, frac, gi0);
    float bi0 = pbi[0], bi = fmaf(pbi[1] - bi0, frac, bi0);
    float gn0 = pgn[0], gn = fmaf(pgn[1] - gn0, frac, gn0);
    float bn0 = pbn[0], bn = fmaf(pbn[1] - bn0, frac, bn0);
    float x = fmaf(gi, ev, bi);

    f32x4_t w0f = *(const f32x4_t*)(W0s + n * 16 + quad * 4);
    f32x4_t b0f = *(const f32x4_t*)(B0s + n * 16 + quad * 4);
    f32x4_t b1f = *(const f32x4_t*)(B1s + n * 16 + quad * 4);
    float b2v = BMs[n * 2], mwv = BMs[n * 2 + 1];
    half4_t a1, a2;
    { union { uint2 u; half4_t h; } cv; cv.u = af1; a1 = cv.h; }
    { union { uint2 u; half4_t h; } cv; cv.u = af2; a2 = cv.h; }
    f32x4_t c2; c2[0] = b2v; c2[1] = b2v; c2[2] = b2v; c2[3] = b2v;

    float yown = 0.0f;
    #pragma unroll
    for (int g = 0; g < 4; ++g) {
      float xg = __shfl(x, g * 16 + l16, 64);
      half4_t bf1;
      #pragma unroll
      for (int k = 0; k < 4; ++k)
        bf1[k] = (_Float16)sinrev(fmaf(xg, w0f[k], b0f[k]));
      f32x4_t d1 = __builtin_amdgcn_mfma_f32_16x16x16f16(a1, bf1, b1f, 0, 0, 0);
      half4_t bf2;
      #pragma unroll
      for (int k = 0; k < 4; ++k)
        bf2[k] = (_Float16)sinrev(d1[k]);
      f32x4_t d2 = __builtin_amdgcn_mfma_f32_16x16x16f16(a2, bf2, c2, 0, 0, 0);
      yown = (quad == g) ? d2[0] : yown;     // lane's own-t row (all rows equal)
    }
    float z = sinrev(yown);
    acc = fmaf(mwv, fmaf(gn, z, bn), acc);
    ev = ev_n; af1 = af1_n; af2 = af2_n;
  }
  part[((size_t)(half * NB + b)) * TT + t_own] = acc;
}

// ---------------- kernel 3: combine partials, x4 repeat, mixer bias --------
__global__ __launch_bounds__(256) void k_mix(
    const float* __restrict__ part,
    const float* __restrict__ mixb,
    float* __restrict__ out) {
  int i = blockIdx.x * 256 + threadIdx.x;   // over B*T
  float s = part[i] + part[NB * TT + i] + mixb[0];
  float4 v = {s, s, s, s};
  *(float4*)(out + 4 * (size_t)i) = v;
}

extern "C" void kernel_launch(void* const* d_in, const int* in_sizes, int n_in,
                              void* d_out, int out_size, void* d_ws, size_t ws_size,
                              hipStream_t stream) {
  const float* exciter = (const float*)d_in[0];
  const float* ce      = (const float*)d_in[1];
  const float* w0  = (const float*)d_in[2];
  const float* b0  = (const float*)d_in[3];
  const float* g0  = (const float*)d_in[4];
  const float* e0  = (const float*)d_in[5];
  const float* w1  = (const float*)d_in[6];
  const float* b1  = (const float*)d_in[7];
  const float* g1  = (const float*)d_in[8];
  const float* e1  = (const float*)d_in[9];
  const float* w2  = (const float*)d_in[10];
  const float* b2  = (const float*)d_in[11];
  const float* g2  = (const float*)d_in[12];
  const float* e2  = (const float*)d_in[13];
  const float* w3  = (const float*)d_in[14];
  const float* b3  = (const float*)d_in[15];
  const float* iscale = (const float*)d_in[16];
  const float* sw0 = (const float*)d_in[17];
  const float* sb0 = (const float*)d_in[18];
  const float* sw1 = (const float*)d_in[19];
  const float* sb1 = (const float*)d_in[20];
  const float* sw2 = (const float*)d_in[21];
  const float* sb2 = (const float*)d_in[22];
  const float* mixw = (const float*)d_in[23];
  const float* mixb = (const float*)d_in[24];

  float* ws = (float*)d_ws;

  hipLaunchKernelGGL(k_prep, dim3(16), dim3(256), 0, stream,
                     iscale, sw0, sb0, sw1, sb1, sw2, sb2, mixw, ws);
  hipLaunchKernelGGL(k_mlp, dim3(512), dim3(256), 0, stream,
                     ce, w0, b0, g0, e0, w1, b1, g1, e1, w2, b2, g2, e2, w3, b3,
                     ws + OFF_FILM);
  hipLaunchKernelGGL(k_shape, dim3(2048), dim3(256), 0, stream,
                     exciter, ws, ws + OFF_PART);
  hipLaunchKernelGGL(k_mix, dim3(1024), dim3(256), 0, stream,
                     ws + OFF_PART, mixb, (float*)d_out);
}

// Round 6
// 258.737 us; speedup vs baseline: 1.0664x; 1.0100x over previous
//
#include <hip/hip_runtime.h>
#include <stdint.h>

#define NB 4
#define NWS 64
#define TT 65536
#define TCC 1024
#define CEE 128
#define WW 16

#define INV2PI 0.15915494309189535f

// ws layout (float offsets)
#define OFF_FILM  0
#define OFF_W0S   (OFF_FILM + NB*256*TCC)     // 1048576
#define OFF_B0S   (OFF_W0S + 1024)
#define OFF_B1S   (OFF_B0S + 1024)
#define OFF_B2S   (OFF_B1S + 1024)
#define OFF_MIX   (OFF_B2S + 64)
#define OFF_AFRAG (OFF_MIX + 64)              // 4096 uint4 = 16384 words (16B aligned)
#define OFF_PART  (OFF_AFRAG + 16384)         // 2*NB*TT floats

typedef _Float16 half4_t __attribute__((ext_vector_type(4)));
typedef float f32x4_t __attribute__((ext_vector_type(4)));

__device__ __forceinline__ float sinrev(float r) {
  // sin(2*pi*r); weights/biases pre-scaled by 1/2pi
#if __has_builtin(__builtin_amdgcn_fractf) && __has_builtin(__builtin_amdgcn_sinf)
  return __builtin_amdgcn_sinf(__builtin_amdgcn_fractf(r));
#else
  float fr = r - floorf(r);
  return __sinf(fr * 6.283185307179586f);
#endif
}

// ---------------- prep: pre-scale shaper weights; pack W1+w2 frags ---------
__global__ __launch_bounds__(256) void k_prep(
    const float* __restrict__ iscale,
    const float* __restrict__ w0, const float* __restrict__ b0,
    const float* __restrict__ w1, const float* __restrict__ b1,
    const float* __restrict__ w2, const float* __restrict__ b2,
    const float* __restrict__ mixw,
    float* __restrict__ ws) {
  int i = blockIdx.x * 256 + threadIdx.x;
  if (i < NWS * WW) {
    int n = i / WW;
    ws[OFF_W0S + i] = w0[i] * iscale[n] * INV2PI;
    ws[OFF_B0S + i] = b0[i] * INV2PI;
    ws[OFF_B1S + i] = b1[i] * INV2PI;
  }
  if (i < NWS) {
    ws[OFF_B2S + i] = b2[i] * INV2PI;
    ws[OFF_MIX + i] = mixw[i];
  }
  if (i < NWS * 64) {
    int n = i >> 6, l = i & 63;
    int m = l & 15, k0 = (l >> 4) * 4;
    // A1-frag: lane l holds W1[n][m][k0+j] / 2pi  (m = l&15, k = quad*4+j)
    union { uint2 u; half4_t h; } cv;
    #pragma unroll
    for (int j = 0; j < 4; ++j)
      cv.h[j] = (_Float16)(w1[(n * 16 + m) * 16 + k0 + j] * INV2PI);
    // A2-frag: A2[m][k] = w2[n][k] / 2pi  (row-independent broadcast)
    union { uint2 u; half4_t h; } c2;
    #pragma unroll
    for (int j = 0; j < 4; ++j)
      c2.h[j] = (_Float16)(w2[n * 16 + k0 + j] * INV2PI);
    uint4 o; o.x = cv.u.x; o.y = cv.u.y; o.z = c2.u.x; o.w = c2.u.y;
    ((uint4*)(ws + OFF_AFRAG))[i] = o;
  }
}

// ---------------- kernel 1: TimeDistributedMLP -> film [B,256,TC] fp32 -----
#define MCOLS 8
__global__ __launch_bounds__(256) void k_mlp(
    const float* __restrict__ ce,
    const float* __restrict__ w0, const float* __restrict__ b0,
    const float* __restrict__ g0, const float* __restrict__ e0,
    const float* __restrict__ w1, const float* __restrict__ b1,
    const float* __restrict__ g1, const float* __restrict__ e1,
    const float* __restrict__ w2, const float* __restrict__ b2,
    const float* __restrict__ g2, const float* __restrict__ e2,
    const float* __restrict__ w3, const float* __restrict__ b3,
    float* __restrict__ film) {
  const int tid = threadIdx.x;
  const int o = tid & 127;
  const int h = tid >> 7;
  const int wvid = tid >> 6;
  const int bx = blockIdx.x;
  const int b = bx >> 7;
  const int tc0 = (bx & 127) * MCOLS;

  __shared__ float wlds[128 * 65];
  __shared__ __align__(16) float xa[CEE * MCOLS];
  __shared__ __align__(16) float xb[CEE * MCOLS];
  __shared__ float red[4][2][4];
  __shared__ float stat[2][MCOLS];

  if (tid < 128) {
    const float* src = ce + ((size_t)(b * CEE + tid)) * TCC + tc0;
    *(float4*)(xa + tid * MCOLS) = *(const float4*)src;
    *(float4*)(xa + tid * MCOLS + 4) = *(const float4*)(src + 4);
  }

  float* xin = xa; float* xout = xb;
  const float* Wp[3] = {w0, w1, w2};
  const float* Bp[3] = {b0, b1, b2};
  const float* Gp[3] = {g0, g1, g2};
  const float* Ep[3] = {e0, e1, e2};

  for (int L = 0; L < 3; ++L) {
    float acc[4];
    float bias = Bp[L][o];
    #pragma unroll
    for (int cc = 0; cc < 4; ++cc) acc[cc] = bias;

    for (int half = 0; half < 2; ++half) {
      __syncthreads();
      const float* wsrc = Wp[L] + half * 64;
      for (int i = tid; i < 4096; i += 256) {
        int oo = i >> 5, cc2 = (i & 31) * 2;
        float2 wv = *(const float2*)(wsrc + (size_t)oo * CEE + cc2);
        wlds[oo * 65 + cc2] = wv.x;
        wlds[oo * 65 + cc2 + 1] = wv.y;
      }
      __syncthreads();
      const float* xcol = xin + half * 64 * MCOLS + h * 4;
      const float* wr = wlds + o * 65;
      #pragma unroll 8
      for (int c = 0; c < 64; ++c) {
        float w = wr[c];
        float4 xv = *(const float4*)(xcol + c * MCOLS);
        acc[0] = fmaf(w, xv.x, acc[0]); acc[1] = fmaf(w, xv.y, acc[1]);
        acc[2] = fmaf(w, xv.z, acc[2]); acc[3] = fmaf(w, xv.w, acc[3]);
      }
    }

    float s[4], q[4];
    #pragma unroll
    for (int cc = 0; cc < 4; ++cc) { s[cc] = acc[cc]; q[cc] = acc[cc] * acc[cc]; }
    #pragma unroll
    for (int m = 1; m < 64; m <<= 1) {
      #pragma unroll
      for (int cc = 0; cc < 4; ++cc) {
        s[cc] += __shfl_xor(s[cc], m, 64);
        q[cc] += __shfl_xor(q[cc], m, 64);
      }
    }
    if ((tid & 63) == 0) {
      #pragma unroll
      for (int cc = 0; cc < 4; ++cc) { red[wvid][0][cc] = s[cc]; red[wvid][1][cc] = q[cc]; }
    }
    __syncthreads();
    if (tid < MCOLS) {
      int hh = tid >> 2, cc = tid & 3;
      float st = red[2 * hh][0][cc] + red[2 * hh + 1][0][cc];
      float qt = red[2 * hh][1][cc] + red[2 * hh + 1][1][cc];
      float mu = st * (1.0f / CEE);
      float var = qt * (1.0f / CEE) - mu * mu;
      stat[0][tid] = mu;
      stat[1][tid] = rsqrtf(var + 1e-5f);
    }
    __syncthreads();
    float g = Gp[L][o], e = Ep[L][o];
    #pragma unroll
    for (int cc = 0; cc < 4; ++cc) {
      int col = h * 4 + cc;
      float v = (acc[cc] - stat[0][col]) * stat[1][col] * g + e;
      v = fmaxf(v, 0.01f * v);
      xout[o * MCOLS + col] = v;
    }
    float* tmp = xin; xin = xout; xout = tmp;
  }

  for (int hh = 0; hh < 2; ++hh) {
    float acc[4];
    float bias = b3[hh * 128 + o];
    #pragma unroll
    for (int cc = 0; cc < 4; ++cc) acc[cc] = bias;
    for (int half = 0; half < 2; ++half) {
      __syncthreads();
      const float* wsrc = w3 + (size_t)hh * 128 * CEE + half * 64;
      for (int i = tid; i < 4096; i += 256) {
        int oo = i >> 5, cc2 = (i & 31) * 2;
        float2 wv = *(const float2*)(wsrc + (size_t)oo * CEE + cc2);
        wlds[oo * 65 + cc2] = wv.x;
        wlds[oo * 65 + cc2 + 1] = wv.y;
      }
      __syncthreads();
      const float* xcol = xin + half * 64 * MCOLS + h * 4;
      const float* wr = wlds + o * 65;
      #pragma unroll 8
      for (int c = 0; c < 64; ++c) {
        float w = wr[c];
        float4 xv = *(const float4*)(xcol + c * MCOLS);
        acc[0] = fmaf(w, xv.x, acc[0]); acc[1] = fmaf(w, xv.y, acc[1]);
        acc[2] = fmaf(w, xv.z, acc[2]); acc[3] = fmaf(w, xv.w, acc[3]);
      }
    }
    float* dst = film + ((size_t)(b * 256 + hh * 128 + o)) * TCC + tc0 + h * 4;
    *(float4*)dst = *(float4*)acc;
  }
}

// ---------------- kernel 2: FiLM + dual-MFMA waveshaper -> partials --------
// grid: 256 t-tiles x 4 batches x 2 channel-halves; block 256 (4 waves x 64 t)
__global__ __launch_bounds__(256, 8) void k_shape(
    const float* __restrict__ exciter,
    const float* __restrict__ ws,
    float* __restrict__ part) {
  const int tid = threadIdx.x;
  const int lane = tid & 63;
  const int wv = tid >> 6;
  const int bx = blockIdx.x;
  const int blk = bx & 255;
  const int b = (bx >> 8) & 3;
  const int half = bx >> 10;
  const int n0 = half * 32;
  const int t0_blk = blk * 256;
  const int tcbase = blk * 4 - 1;

  __shared__ float FLraw[32 * 24];                 // [n][param 0..3][j 0..5]
  __shared__ float FLp[32 * 36];                   // [n][p 0..2][(val,diff) x6]
  __shared__ float Sraw[8], Spair[12];
  __shared__ __align__(16) float W0s[32 * 16], B0s[32 * 16], B1s[32 * 16];
  __shared__ float B2s[32], MWs[32];

  for (int i = tid; i < 512; i += 256) {
    W0s[i] = ws[OFF_W0S + n0 * 16 + i];
    B0s[i] = ws[OFF_B0S + n0 * 16 + i];
    B1s[i] = ws[OFF_B1S + n0 * 16 + i];
  }
  if (tid < 32) {
    B2s[tid] = ws[OFF_B2S + n0 + tid];
    MWs[tid] = ws[OFF_MIX + n0 + tid];
  }
  for (int i = tid; i < 768; i += 256) {
    int n = i / 24, r = i - n * 24, p = r / 6, j = r - p * 6;
    int tc = tcbase + j; tc = tc < 0 ? 0 : (tc > 1023 ? 1023 : tc);
    FLraw[i] = ws[OFF_FILM + ((size_t)(b * 256 + p * 64 + n0 + n)) * TCC + tc];
  }
  __syncthreads();
  // (val,diff) pairs for gi, bi, gn' (= mw*gn); sum S_j = sum_n mw*bn
  for (int i = tid; i < 576; i += 256) {
    int n = i / 18, r = i - n * 18, p = r / 6, j = r - p * 6;
    float v = FLraw[n * 24 + p * 6 + j];
    float vn = (j < 5) ? FLraw[n * 24 + p * 6 + j + 1] : v;
    float sc = (p == 2) ? MWs[n] : 1.0f;
    FLp[n * 36 + p * 12 + 2 * j] = v * sc;
    FLp[n * 36 + p * 12 + 2 * j + 1] = (vn - v) * sc;
  }
  if (tid < 6) {
    float s = 0.0f;
    for (int n = 0; n < 32; ++n) s += MWs[n] * FLraw[n * 24 + 18 + tid];
    Sraw[tid] = s;
  }
  __syncthreads();
  if (tid < 6) {
    Spair[2 * tid] = Sraw[tid];
    Spair[2 * tid + 1] = (tid < 5) ? Sraw[tid + 1] - Sraw[tid] : 0.0f;
  }
  __syncthreads();

  const int t_own = t0_blk + wv * 64 + lane;
  float pos = ((float)t_own + 0.5f) * (1.0f / 64.0f) - 0.5f;
  pos = fminf(fmaxf(pos, 0.0f), 1023.0f);
  float fi = floorf(pos);
  int i0 = (int)fi;
  const float frac = pos - fi;
  const int j0 = i0 - tcbase;        // in [0,4]; pair (val,diff) handles clamp

  const int quad = lane >> 4;
  const int l16 = lane & 15;

  float acc = 0.0f;
  const float* excp = exciter + ((size_t)(b * NWS + n0)) * TT + t_own;
  const uint4* afp = (const uint4*)(ws + OFF_AFRAG) + (size_t)n0 * 64 + lane;

  f32x4_t czero; czero[0] = 0.f; czero[1] = 0.f; czero[2] = 0.f; czero[3] = 0.f;

  float ev = excp[0];
  uint4 af = afp[0];
  for (int n = 0; n < 32; ++n) {
    float ev_n = 0.f; uint4 af_n = af;
    if (n < 31) {
      ev_n = excp[(size_t)(n + 1) * TT];
      af_n = afp[(n + 1) * 64];
    }
    const float* fp = FLp + n * 36 + 2 * j0;
    float2 gp = *(const float2*)(fp);
    float2 bp = *(const float2*)(fp + 12);
    float2 np = *(const float2*)(fp + 24);
    float gi = fmaf(gp.y, frac, gp.x);
    float bi = fmaf(bp.y, frac, bp.x);
    float gnp = fmaf(np.y, frac, np.x);
    float x = fmaf(gi, ev, bi);

    f32x4_t w0f = *(const f32x4_t*)(W0s + n * 16 + quad * 4);
    f32x4_t b0f = *(const f32x4_t*)(B0s + n * 16 + quad * 4);
    f32x4_t b1f = *(const f32x4_t*)(B1s + n * 16 + quad * 4);
    float b2v = B2s[n];
    half4_t a1, a2;
    { union { uint2 u; half4_t h; } cv; cv.u.x = af.x; cv.u.y = af.y; a1 = cv.h; }
    { union { uint2 u; half4_t h; } cv; cv.u.x = af.z; cv.u.y = af.w; a2 = cv.h; }

    float yown = 0.0f;
    #pragma unroll
    for (int g = 0; g < 4; ++g) {
      float xg = __shfl(x, g * 16 + l16, 64);
      half4_t bf1;
      #pragma unroll
      for (int k = 0; k < 4; ++k)
        bf1[k] = (_Float16)sinrev(fmaf(xg, w0f[k], b0f[k]));
      f32x4_t d1 = __builtin_amdgcn_mfma_f32_16x16x16f16(a1, bf1, b1f, 0, 0, 0);
      half4_t bf2;
      #pragma unroll
      for (int k = 0; k < 4; ++k)
        bf2[k] = (_Float16)sinrev(d1[k]);
      f32x4_t d2 = __builtin_amdgcn_mfma_f32_16x16x16f16(a2, bf2, czero, 0, 0, 0);
      yown = (quad == g) ? d2[0] : yown;   // all D2 rows equal; pick own group
    }
    float z = sinrev(yown + b2v);
    acc = fmaf(gnp, z, acc);
    ev = ev_n; af = af_n;
  }
  float2 sp = *(const float2*)(Spair + 2 * j0);
  part[((size_t)(half * NB + b)) * TT + t_own] = acc + fmaf(sp.y, frac, sp.x);
}

// ---------------- kernel 3: combine partials, x4 repeat, mixer bias --------
__global__ __launch_bounds__(256) void k_mix(
    const float* __restrict__ part,
    const float* __restrict__ mixb,
    float* __restrict__ out) {
  int idx = blockIdx.x * 256 + threadIdx.x;   // over B*T/4
  float m = mixb[0];
  float4 a = ((const float4*)part)[idx];
  float4 c = ((const float4*)(part + NB * TT))[idx];
  float4* o = (float4*)(out + (size_t)idx * 16);
  float s0 = a.x + c.x + m, s1 = a.y + c.y + m, s2 = a.z + c.z + m, s3 = a.w + c.w + m;
  o[0] = make_float4(s0, s0, s0, s0);
  o[1] = make_float4(s1, s1, s1, s1);
  o[2] = make_float4(s2, s2, s2, s2);
  o[3] = make_float4(s3, s3, s3, s3);
}

extern "C" void kernel_launch(void* const* d_in, const int* in_sizes, int n_in,
                              void* d_out, int out_size, void* d_ws, size_t ws_size,
                              hipStream_t stream) {
  const float* exciter = (const float*)d_in[0];
  const float* ce      = (const float*)d_in[1];
  const float* w0  = (const float*)d_in[2];
  const float* b0  = (const float*)d_in[3];
  const float* g0  = (const float*)d_in[4];
  const float* e0  = (const float*)d_in[5];
  const float* w1  = (const float*)d_in[6];
  const float* b1  = (const float*)d_in[7];
  const float* g1  = (const float*)d_in[8];
  const float* e1  = (const float*)d_in[9];
  const float* w2  = (const float*)d_in[10];
  const float* b2  = (const float*)d_in[11];
  const float* g2  = (const float*)d_in[12];
  const float* e2  = (const float*)d_in[13];
  const float* w3  = (const float*)d_in[14];
  const float* b3  = (const float*)d_in[15];
  const float* iscale = (const float*)d_in[16];
  const float* sw0 = (const float*)d_in[17];
  const float* sb0 = (const float*)d_in[18];
  const float* sw1 = (const float*)d_in[19];
  const float* sb1 = (const float*)d_in[20];
  const float* sw2 = (const float*)d_in[21];
  const float* sb2 = (const float*)d_in[22];
  const float* mixw = (const float*)d_in[23];
  const float* mixb = (const float*)d_in[24];

  float* ws = (float*)d_ws;

  hipLaunchKernelGGL(k_prep, dim3(16), dim3(256), 0, stream,
                     iscale, sw0, sb0, sw1, sb1, sw2, sb2, mixw, ws);
  hipLaunchKernelGGL(k_mlp, dim3(512), dim3(256), 0, stream,
                     ce, w0, b0, g0, e0, w1, b1, g1, e1, w2, b2, g2, e2, w3, b3,
                     ws + OFF_FILM);
  hipLaunchKernelGGL(k_shape, dim3(2048), dim3(256), 0, stream,
                     exciter, ws, ws + OFF_PART);
  hipLaunchKernelGGL(k_mix, dim3(256), dim3(256), 0, stream,
                     ws + OFF_PART, mixb, (float*)d_out);
}

// Round 8
// 249.400 us; speedup vs baseline: 1.1063x; 1.0374x over previous
//
#include <hip/hip_runtime.h>
#include <stdint.h>

#define NB 4
#define NWS 64
#define TT 65536
#define TCC 1024
#define CEE 128
#define WW 16

#define INV2PI 0.15915494309189535f

// ws layout (float offsets)
#define OFF_FILM  0                           // 1048576
#define OFF_SB    (OFF_FILM + NB*256*TCC)     // 4096: S[b][tc] = sum_n mw*bn
#define OFF_W0S   (OFF_SB + NB*TCC)           // 1024
#define OFF_B0S   (OFF_W0S + 1024)
#define OFF_B1S   (OFF_B0S + 1024)
#define OFF_B2S   (OFF_B1S + 1024)            // 64
#define OFF_AFRAG (OFF_B2S + 64)              // 4096 uint4 = 16384 floats
#define OFF_PART  (OFF_AFRAG + 16384)         // 4*NB*TT floats

typedef _Float16 half4_t __attribute__((ext_vector_type(4)));
typedef _Float16 half2_t __attribute__((ext_vector_type(2)));
typedef __fp16 fp16x2_t __attribute__((ext_vector_type(2)));
typedef float f32x4_t __attribute__((ext_vector_type(4)));

union H4 { half4_t h4; half2_t h2[2]; fp16x2_t f2[2]; uint2 u; };

__device__ __forceinline__ float sinrev(float r) {
  // sin(2*pi*r); weights/biases pre-scaled by 1/2pi
#if __has_builtin(__builtin_amdgcn_fractf) && __has_builtin(__builtin_amdgcn_sinf)
  return __builtin_amdgcn_sinf(__builtin_amdgcn_fractf(r));
#else
  float fr = r - floorf(r);
  return __sinf(fr * 6.283185307179586f);
#endif
}

// ---------------- kernel 1: prep (blocks 0-15) + MLP -> film + S -----------
#define MCOLS 8
__global__ __launch_bounds__(256) void k_mlp(
    const float* __restrict__ ce,
    const float* __restrict__ w0, const float* __restrict__ b0,
    const float* __restrict__ g0, const float* __restrict__ e0,
    const float* __restrict__ w1, const float* __restrict__ b1,
    const float* __restrict__ g1, const float* __restrict__ e1,
    const float* __restrict__ w2, const float* __restrict__ b2,
    const float* __restrict__ g2, const float* __restrict__ e2,
    const float* __restrict__ w3, const float* __restrict__ b3,
    const float* __restrict__ iscale,
    const float* __restrict__ sw0, const float* __restrict__ sb0,
    const float* __restrict__ sw1, const float* __restrict__ sb1,
    const float* __restrict__ sw2, const float* __restrict__ sb2,
    const float* __restrict__ mixw,
    float* __restrict__ ws) {
  const int tid = threadIdx.x;
  const int bx = blockIdx.x;

  // ---- fused prep (weight pre-scale + MFMA fragment packing) ----
  if (bx < 16) {
    int i = bx * 256 + tid;           // 0..4095
    if (i < NWS * WW) {
      int n = i / WW;
      ws[OFF_W0S + i] = sw0[i] * iscale[n] * INV2PI;
      ws[OFF_B0S + i] = sb0[i] * INV2PI;
      ws[OFF_B1S + i] = sb1[i] * INV2PI;
    }
    if (i < NWS) ws[OFF_B2S + i] = sb2[i] * INV2PI;
    {
      int n = i >> 6, l = i & 63;
      int m = l & 15, k0 = (l >> 4) * 4;
      H4 a1, a2;
      #pragma unroll
      for (int j = 0; j < 4; ++j) {
        a1.h4[j] = (_Float16)(sw1[(n * 16 + m) * 16 + k0 + j] * INV2PI);
        a2.h4[j] = (_Float16)(sw2[n * 16 + k0 + j] * INV2PI);
      }
      uint4 o; o.x = a1.u.x; o.y = a1.u.y; o.z = a2.u.x; o.w = a2.u.y;
      ((uint4*)(ws + OFF_AFRAG))[i] = o;
    }
  }

  const int o = tid & 127;
  const int h = tid >> 7;
  const int wvid = tid >> 6;
  const int b = bx >> 7;
  const int tc0 = (bx & 127) * MCOLS;
  float* film = ws + OFF_FILM;

  __shared__ float wlds[128 * 65];
  __shared__ __align__(16) float xa[CEE * MCOLS];
  __shared__ __align__(16) float xb[CEE * MCOLS];
  __shared__ float red[4][2][4];
  __shared__ float stat[2][MCOLS];

  if (tid < 128) {
    const float* src = ce + ((size_t)(b * CEE + tid)) * TCC + tc0;
    *(float4*)(xa + tid * MCOLS) = *(const float4*)src;
    *(float4*)(xa + tid * MCOLS + 4) = *(const float4*)(src + 4);
  }

  float* xin = xa; float* xout = xb;
  const float* Wp[3] = {w0, w1, w2};
  const float* Bp[3] = {b0, b1, b2};
  const float* Gp[3] = {g0, g1, g2};
  const float* Ep[3] = {e0, e1, e2};

  for (int L = 0; L < 3; ++L) {
    float acc[4];
    float bias = Bp[L][o];
    #pragma unroll
    for (int cc = 0; cc < 4; ++cc) acc[cc] = bias;

    for (int half = 0; half < 2; ++half) {
      __syncthreads();
      const float* wsrc = Wp[L] + half * 64;
      for (int i = tid; i < 4096; i += 256) {
        int oo = i >> 5, cc2 = (i & 31) * 2;
        float2 wv = *(const float2*)(wsrc + (size_t)oo * CEE + cc2);
        wlds[oo * 65 + cc2] = wv.x;
        wlds[oo * 65 + cc2 + 1] = wv.y;
      }
      __syncthreads();
      const float* xcol = xin + half * 64 * MCOLS + h * 4;
      const float* wr = wlds + o * 65;
      #pragma unroll 8
      for (int c = 0; c < 64; ++c) {
        float w = wr[c];
        float4 xv = *(const float4*)(xcol + c * MCOLS);
        acc[0] = fmaf(w, xv.x, acc[0]); acc[1] = fmaf(w, xv.y, acc[1]);
        acc[2] = fmaf(w, xv.z, acc[2]); acc[3] = fmaf(w, xv.w, acc[3]);
      }
    }

    float s[4], q[4];
    #pragma unroll
    for (int cc = 0; cc < 4; ++cc) { s[cc] = acc[cc]; q[cc] = acc[cc] * acc[cc]; }
    #pragma unroll
    for (int m = 1; m < 64; m <<= 1) {
      #pragma unroll
      for (int cc = 0; cc < 4; ++cc) {
        s[cc] += __shfl_xor(s[cc], m, 64);
        q[cc] += __shfl_xor(q[cc], m, 64);
      }
    }
    if ((tid & 63) == 0) {
      #pragma unroll
      for (int cc = 0; cc < 4; ++cc) { red[wvid][0][cc] = s[cc]; red[wvid][1][cc] = q[cc]; }
    }
    __syncthreads();
    if (tid < MCOLS) {
      int hh = tid >> 2, cc = tid & 3;
      float st = red[2 * hh][0][cc] + red[2 * hh + 1][0][cc];
      float qt = red[2 * hh][1][cc] + red[2 * hh + 1][1][cc];
      float mu = st * (1.0f / CEE);
      float var = qt * (1.0f / CEE) - mu * mu;
      stat[0][tid] = mu;
      stat[1][tid] = rsqrtf(var + 1e-5f);
    }
    __syncthreads();
    float g = Gp[L][o], e = Ep[L][o];
    #pragma unroll
    for (int cc = 0; cc < 4; ++cc) {
      int col = h * 4 + cc;
      float v = (acc[cc] - stat[0][col]) * stat[1][col] * g + e;
      v = fmaxf(v, 0.01f * v);
      xout[o * MCOLS + col] = v;
    }
    float* tmp = xin; xin = xout; xout = tmp;
  }

  for (int hh = 0; hh < 2; ++hh) {
    float acc[4];
    float bias = b3[hh * 128 + o];
    #pragma unroll
    for (int cc = 0; cc < 4; ++cc) acc[cc] = bias;
    for (int half = 0; half < 2; ++half) {
      __syncthreads();
      const float* wsrc = w3 + (size_t)hh * 128 * CEE + half * 64;
      for (int i = tid; i < 4096; i += 256) {
        int oo = i >> 5, cc2 = (i & 31) * 2;
        float2 wv = *(const float2*)(wsrc + (size_t)oo * CEE + cc2);
        wlds[oo * 65 + cc2] = wv.x;
        wlds[oo * 65 + cc2 + 1] = wv.y;
      }
      __syncthreads();
      const float* xcol = xin + half * 64 * MCOLS + h * 4;
      const float* wr = wlds + o * 65;
      #pragma unroll 8
      for (int c = 0; c < 64; ++c) {
        float w = wr[c];
        float4 xv = *(const float4*)(xcol + c * MCOLS);
        acc[0] = fmaf(w, xv.x, acc[0]); acc[1] = fmaf(w, xv.y, acc[1]);
        acc[2] = fmaf(w, xv.z, acc[2]); acc[3] = fmaf(w, xv.w, acc[3]);
      }
    }
    float* dst = film + ((size_t)(b * 256 + hh * 128 + o)) * TCC + tc0 + h * 4;
    *(float4*)dst = *(float4*)acc;

    // S epilogue: rows 192..255 hold beta_n; reduce mw-weighted sum per col
    if (hh == 1 && ((tid >> 6) & 1)) {      // waves 1 and 3: o in [64,128)
      int n = o - 64;
      float mwn = mixw[n];
      float sv[4];
      #pragma unroll
      for (int cc = 0; cc < 4; ++cc) sv[cc] = mwn * acc[cc];
      #pragma unroll
      for (int m = 1; m < 64; m <<= 1) {
        #pragma unroll
        for (int cc = 0; cc < 4; ++cc) sv[cc] += __shfl_xor(sv[cc], m, 64);
      }
      if ((tid & 63) == 0) {
        #pragma unroll
        for (int cc = 0; cc < 4; ++cc)
          ws[OFF_SB + b * TCC + tc0 + h * 4 + cc] = sv[cc];
      }
    }
  }
}

// ---------------- kernel 2: FiLM + dual-MFMA waveshaper -> partials --------
// grid: 256 t-tiles x 4 batches x 4 channel-quarters; block 256 (4 waves)
__global__ __launch_bounds__(256, 8) void k_shape(
    const float* __restrict__ exciter,
    const float* __restrict__ ws,
    const float* __restrict__ mixw,
    float* __restrict__ part) {
  const int tid = threadIdx.x;
  const int lane = tid & 63;
  const int wv = tid >> 6;
  const int bx = blockIdx.x;
  const int blk = bx & 255;
  const int b = (bx >> 8) & 3;
  const int quarter = bx >> 10;
  const int n0 = quarter * 16;
  const int t0_blk = blk * 256;
  const int tcbase = blk * 4 - 1;

  __shared__ __align__(16) float FLp[16 * 48];    // [n][j 0..5][8]: gv,gd,bv,bd,nv,nd,-,-
  __shared__ float Spair[12];
  __shared__ __align__(16) float W0s[16 * 16], B0s[16 * 16], B1s[16 * 16];
  __shared__ float B2s[16];

  if (tid < 16 * 16) {
    W0s[tid] = ws[OFF_W0S + n0 * 16 + tid];
    B0s[tid] = ws[OFF_B0S + n0 * 16 + tid];
    B1s[tid] = ws[OFF_B1S + n0 * 16 + tid];
  }
  if (tid < 16) B2s[tid] = ws[OFF_B2S + n0 + tid];
  // film (val,diff) pairs: gi, bi, gn' (= mw*gn)
  if (tid < 96) {
    int n = tid / 6, j = tid - n * 6;
    int tc = tcbase + j; tc = tc < 0 ? 0 : (tc > 1023 ? 1023 : tc);
    int tcn = tcbase + j + 1; tcn = tcn < 0 ? 0 : (tcn > 1023 ? 1023 : tcn);
    const float* fb = ws + OFF_FILM + ((size_t)(b * 256 + n0 + n)) * TCC;
    float g_v = fb[tc], g_n = fb[tcn];
    float b_v = fb[64 * TCC + tc], b_n = fb[64 * TCC + tcn];
    float n_v = fb[128 * TCC + tc], n_n = fb[128 * TCC + tcn];
    float mwn = mixw[n0 + n];
    float* d = FLp + n * 48 + j * 8;
    d[0] = g_v; d[1] = g_n - g_v;
    d[2] = b_v; d[3] = b_n - b_v;
    d[4] = n_v * mwn; d[5] = (n_n - n_v) * mwn;
  }
  if (tid >= 96 && tid < 102 && quarter == 0) {
    int j = tid - 96;
    int tc = tcbase + j; tc = tc < 0 ? 0 : (tc > 1023 ? 1023 : tc);
    int tcn = tcbase + j + 1; tcn = tcn < 0 ? 0 : (tcn > 1023 ? 1023 : tcn);
    float s0 = ws[OFF_SB + b * TCC + tc];
    float s1 = ws[OFF_SB + b * TCC + tcn];
    Spair[2 * j] = s0; Spair[2 * j + 1] = s1 - s0;
  }
  __syncthreads();

  const int t_own = t0_blk + wv * 64 + lane;
  float pos = ((float)t_own + 0.5f) * (1.0f / 64.0f) - 0.5f;
  pos = fminf(fmaxf(pos, 0.0f), 1023.0f);
  float fi = floorf(pos);
  int i0 = (int)fi;
  const float frac = pos - fi;
  const int j0 = i0 - tcbase;        // in [0,4]

  const int quad = lane >> 4;
  const int l16 = lane & 15;

  float acc = 0.0f;
  const float* excp = exciter + ((size_t)(b * NWS + n0)) * TT + t_own;
  const uint4* afp = (const uint4*)(ws + OFF_AFRAG) + (size_t)n0 * 64 + lane;

  f32x4_t czero; czero[0] = 0.f; czero[1] = 0.f; czero[2] = 0.f; czero[3] = 0.f;

  float ev = excp[0];
  uint4 af = afp[0];
  for (int n = 0; n < 16; ++n) {
    float ev_n = 0.f; uint4 af_n = af;
    if (n < 15) {
      ev_n = excp[(size_t)(n + 1) * TT];
      af_n = afp[(n + 1) * 64];
    }
    const float* fp = FLp + n * 48 + j0 * 8;
    float4 gb = *(const float4*)(fp);
    float2 np = *(const float2*)(fp + 4);
    float gi = fmaf(gb.y, frac, gb.x);
    float bi = fmaf(gb.w, frac, gb.z);
    float gnp = fmaf(np.y, frac, np.x);
    float x = fmaf(gi, ev, bi);

    f32x4_t w0f = *(const f32x4_t*)(W0s + n * 16 + quad * 4);
    f32x4_t b0f = *(const f32x4_t*)(B0s + n * 16 + quad * 4);
    f32x4_t b1f = *(const f32x4_t*)(B1s + n * 16 + quad * 4);
    float b2v = B2s[n];
    H4 a1, a2;
    a1.u.x = af.x; a1.u.y = af.y;
    a2.u.x = af.z; a2.u.y = af.w;

    float yown = 0.0f;
    #pragma unroll
    for (int g = 0; g < 4; ++g) {
      float xg = __shfl(x, g * 16 + l16, 64);
      float s0 = sinrev(fmaf(xg, w0f[0], b0f[0]));
      float s1 = sinrev(fmaf(xg, w0f[1], b0f[1]));
      float s2 = sinrev(fmaf(xg, w0f[2], b0f[2]));
      float s3 = sinrev(fmaf(xg, w0f[3], b0f[3]));
      H4 bf1;
      bf1.f2[0] = __builtin_amdgcn_cvt_pkrtz(s0, s1);
      bf1.f2[1] = __builtin_amdgcn_cvt_pkrtz(s2, s3);
      f32x4_t d1 = __builtin_amdgcn_mfma_f32_16x16x16f16(a1.h4, bf1.h4, b1f, 0, 0, 0);
      float u0 = sinrev(d1[0]);
      float u1 = sinrev(d1[1]);
      float u2 = sinrev(d1[2]);
      float u3 = sinrev(d1[3]);
      H4 bf2;
      bf2.f2[0] = __builtin_amdgcn_cvt_pkrtz(u0, u1);
      bf2.f2[1] = __builtin_amdgcn_cvt_pkrtz(u2, u3);
      f32x4_t d2 = __builtin_amdgcn_mfma_f32_16x16x16f16(a2.h4, bf2.h4, czero, 0, 0, 0);
      yown = (quad == g) ? d2[0] : yown;   // all D2 rows equal; pick own group
    }
    float z = sinrev(yown + b2v);
    acc = fmaf(gnp, z, acc);
    ev = ev_n; af = af_n;
  }
  if (quarter == 0) {
    float2 sp = *(const float2*)(Spair + 2 * j0);
    acc += fmaf(sp.y, frac, sp.x);
  }
  part[((size_t)(quarter * NB + b)) * TT + t_own] = acc;
}

// ---------------- kernel 3: combine partials, x4 repeat, mixer bias --------
__global__ __launch_bounds__(256) void k_mix(
    const float* __restrict__ part,
    const float* __restrict__ mixb,
    float* __restrict__ out) {
  int idx = blockIdx.x * 256 + threadIdx.x;   // over B*T/4
  float m = mixb[0];
  float4 a = ((const float4*)part)[idx];
  float4 c = ((const float4*)(part + (size_t)NB * TT))[idx];
  float4 d = ((const float4*)(part + (size_t)2 * NB * TT))[idx];
  float4 e = ((const float4*)(part + (size_t)3 * NB * TT))[idx];
  float4* o = (float4*)(out + (size_t)idx * 16);
  float s0 = a.x + c.x + d.x + e.x + m;
  float s1 = a.y + c.y + d.y + e.y + m;
  float s2 = a.z + c.z + d.z + e.z + m;
  float s3 = a.w + c.w + d.w + e.w + m;
  o[0] = make_float4(s0, s0, s0, s0);
  o[1] = make_float4(s1, s1, s1, s1);
  o[2] = make_float4(s2, s2, s2, s2);
  o[3] = make_float4(s3, s3, s3, s3);
}

extern "C" void kernel_launch(void* const* d_in, const int* in_sizes, int n_in,
                              void* d_out, int out_size, void* d_ws, size_t ws_size,
                              hipStream_t stream) {
  const float* exciter = (const float*)d_in[0];
  const float* ce      = (const float*)d_in[1];
  const float* w0  = (const float*)d_in[2];
  const float* b0  = (const float*)d_in[3];
  const float* g0  = (const float*)d_in[4];
  const float* e0  = (const float*)d_in[5];
  const float* w1  = (const float*)d_in[6];
  const float* b1  = (const float*)d_in[7];
  const float* g1  = (const float*)d_in[8];
  const float* e1  = (const float*)d_in[9];
  const float* w2  = (const float*)d_in[10];
  const float* b2  = (const float*)d_in[11];
  const float* g2  = (const float*)d_in[12];
  const float* e2  = (const float*)d_in[13];
  const float* w3  = (const float*)d_in[14];
  const float* b3  = (const float*)d_in[15];
  const float* iscale = (const float*)d_in[16];
  const float* sw0 = (const float*)d_in[17];
  const float* sb0 = (const float*)d_in[18];
  const float* sw1 = (const float*)d_in[19];
  const float* sb1 = (const float*)d_in[20];
  const float* sw2 = (const float*)d_in[21];
  const float* sb2 = (const float*)d_in[22];
  const float* mixw = (const float*)d_in[23];
  const float* mixb = (const float*)d_in[24];

  float* ws = (float*)d_ws;

  hipLaunchKernelGGL(k_mlp, dim3(512), dim3(256), 0, stream,
                     ce, w0, b0, g0, e0, w1, b1, g1, e1, w2, b2, g2, e2, w3, b3,
                     iscale, sw0, sb0, sw1, sb1, sw2, sb2, mixw, ws);
  hipLaunchKernelGGL(k_shape, dim3(4096), dim3(256), 0, stream,
                     exciter, ws, mixw, ws + OFF_PART);
  hipLaunchKernelGGL(k_mix, dim3(256), dim3(256), 0, stream,
                     ws + OFF_PART, mixb, (float*)d_out);
}

// Round 9
// 210.622 us; speedup vs baseline: 1.3100x; 1.1841x over previous
//
#include <hip/hip_runtime.h>
#include <stdint.h>

#define NB 4
#define NWS 64
#define TT 65536
#define TCC 1024
#define CEE 128
#define WW 16

#define INV2PI 0.15915494309189535f

// ws layout (float offsets)
#define OFF_FILM  0                           // 1048576
#define OFF_SB    (OFF_FILM + NB*256*TCC)     // 4096: S[b][tc] = sum_n mw*bn
#define OFF_W0S   (OFF_SB + NB*TCC)           // 1024
#define OFF_B0S   (OFF_W0S + 1024)
#define OFF_B1S   (OFF_B0S + 1024)
#define OFF_B2S   (OFF_B1S + 1024)            // 64
#define OFF_AFRAG (OFF_B2S + 64)              // 4096 uint4 = 16384 floats
#define OFF_WF    (OFF_AFRAG + 16384)         // 12288 uint4 = 49152 floats (hidden W frags)
#define OFF_W3F   (OFF_WF + 49152)            // 8192 uint4 = 32768 floats (final W frags)
#define OFF_PART  (OFF_W3F + 32768)           // 4*NB*TT floats

typedef _Float16 half4_t __attribute__((ext_vector_type(4)));
typedef _Float16 half2_t __attribute__((ext_vector_type(2)));
typedef __fp16 fp16x2_t __attribute__((ext_vector_type(2)));
typedef float f32x4_t __attribute__((ext_vector_type(4)));

union H4 { half4_t h4; half2_t h2[2]; fp16x2_t f2[2]; uint2 u; };

__device__ __forceinline__ float sinrev(float r) {
  // sin(2*pi*r); args bounded |r| < ~128 revolutions (< HW ±256 limit)
  return __builtin_amdgcn_sinf(r);
}

// ---------------- prep: shaper weights + MLP weight fragments --------------
__global__ __launch_bounds__(256) void k_prep(
    const float* __restrict__ iscale,
    const float* __restrict__ sw0, const float* __restrict__ sb0,
    const float* __restrict__ sw1, const float* __restrict__ sb1,
    const float* __restrict__ sw2, const float* __restrict__ sb2,
    const float* __restrict__ m0, const float* __restrict__ m1,
    const float* __restrict__ m2, const float* __restrict__ m3,
    float* __restrict__ ws) {
  const int tid = threadIdx.x;
  const int bx = blockIdx.x;
  if (bx < 16) {
    int i = bx * 256 + tid;             // 0..4095
    if (i < NWS * WW) {
      int n = i / WW;
      ws[OFF_W0S + i] = sw0[i] * iscale[n] * INV2PI;
      ws[OFF_B0S + i] = sb0[i] * INV2PI;
      ws[OFF_B1S + i] = sb1[i] * INV2PI;
    }
    if (i < NWS) ws[OFF_B2S + i] = sb2[i] * INV2PI;
    {
      int n = i >> 6, l = i & 63;
      int m = l & 15, k0 = (l >> 4) * 4;
      H4 a1, a2;
      #pragma unroll
      for (int j = 0; j < 4; ++j) {
        a1.h4[j] = (_Float16)(sw1[(n * 16 + m) * 16 + k0 + j] * INV2PI);
        a2.h4[j] = (_Float16)(sw2[n * 16 + k0 + j] * INV2PI);
      }
      uint4 o; o.x = a1.u.x; o.y = a1.u.y; o.z = a2.u.x; o.w = a2.u.y;
      ((uint4*)(ws + OFF_AFRAG))[i] = o;
    }
  } else if (bx < 64) {
    // hidden-layer W fragments: B[k][n=ch]: lane holds W[ct*16+l16][kt*16+quad*4+j]
    int i = (bx - 16) * 256 + tid;      // 0..12287 = ((L*8+kt)*8+ct)*64+lane
    int l = i & 63, ct = (i >> 6) & 7, kt = (i >> 9) & 7, L = i >> 12;
    const float* W = (L == 0) ? m0 : (L == 1 ? m1 : m2);
    int o = ct * 16 + (l & 15);
    int k0 = kt * 16 + (l >> 4) * 4;
    H4 hi, lo;
    #pragma unroll
    for (int j = 0; j < 4; ++j) {
      float v = W[o * CEE + k0 + j];
      _Float16 h = (_Float16)v;
      hi.h4[j] = h;
      lo.h4[j] = (_Float16)(v - (float)h);
    }
    uint4 q; q.x = hi.u.x; q.y = hi.u.y; q.z = lo.u.x; q.w = lo.u.y;
    ((uint4*)(ws + OFF_WF))[i] = q;
  } else {
    // final-layer (CE->256) fragments: (kt*16 + ct)*64 + lane
    int i = (bx - 64) * 256 + tid;      // 0..8191
    int l = i & 63, ct = (i >> 6) & 15, kt = i >> 10;
    int o = ct * 16 + (l & 15);
    int k0 = kt * 16 + (l >> 4) * 4;
    H4 hi, lo;
    #pragma unroll
    for (int j = 0; j < 4; ++j) {
      float v = m3[o * CEE + k0 + j];
      _Float16 h = (_Float16)v;
      hi.h4[j] = h;
      lo.h4[j] = (_Float16)(v - (float)h);
    }
    uint4 q; q.x = hi.u.x; q.y = hi.u.y; q.z = lo.u.x; q.w = lo.u.y;
    ((uint4*)(ws + OFF_W3F))[i] = q;
  }
}

// pack x (16 pos x 128 ch fp32 in h) into MFMA A-fragments, f16 hi/lo split
__device__ __forceinline__ void pack_frags(
    const float* h, uint2* XH, uint2* XL,
    const float* MU, const float* RS,
    const float* __restrict__ g, const float* __restrict__ e,
    bool doLN, int tid) {
  #pragma unroll
  for (int i = 0; i < 2; ++i) {
    int w = tid + i * 256;
    int l = w & 63, kt = w >> 6;
    int m = l & 15, k0 = kt * 16 + (l >> 4) * 4;
    float x[4];
    #pragma unroll
    for (int j = 0; j < 4; ++j) {
      float v = h[m * 137 + k0 + j];
      if (doLN) {
        v = (v - MU[m]) * RS[m] * g[k0 + j] + e[k0 + j];
        v = fmaxf(v, 0.01f * v);
      }
      x[j] = v;
    }
    H4 hi;
    hi.f2[0] = __builtin_amdgcn_cvt_pkrtz(x[0], x[1]);
    hi.f2[1] = __builtin_amdgcn_cvt_pkrtz(x[2], x[3]);
    float l0 = x[0] - (float)hi.h4[0];
    float l1 = x[1] - (float)hi.h4[1];
    float l2 = x[2] - (float)hi.h4[2];
    float l3 = x[3] - (float)hi.h4[3];
    H4 lo;
    lo.f2[0] = __builtin_amdgcn_cvt_pkrtz(l0, l1);
    lo.f2[1] = __builtin_amdgcn_cvt_pkrtz(l2, l3);
    XH[kt * 64 + l] = hi.u;
    XL[kt * 64 + l] = lo.u;
  }
}

// ---------------- kernel 1: MFMA TimeDistributedMLP -> film + S ------------
// grid: 4 b x 64 tc-tiles = 256 blocks; block 256 threads (4 waves)
__global__ __launch_bounds__(256) void k_mlp(
    const float* __restrict__ ce,
    const float* __restrict__ b0, const float* __restrict__ g0, const float* __restrict__ e0,
    const float* __restrict__ b1, const float* __restrict__ g1, const float* __restrict__ e1,
    const float* __restrict__ b2, const float* __restrict__ g2, const float* __restrict__ e2,
    const float* __restrict__ b3,
    const float* __restrict__ mixw,
    float* __restrict__ ws) {
  const int tid = threadIdx.x;
  const int lane = tid & 63;
  const int wv = tid >> 6;
  const int l16 = lane & 15;
  const int quad = lane >> 4;
  const int bx = blockIdx.x;
  const int b = bx >> 6;
  const int tc0 = (bx & 63) * 16;

  __shared__ float h[16 * 137];        // [pos][ch] fp32
  __shared__ float h2[16 * 265];       // final [pos][ch256]
  __shared__ uint2 XH[8 * 64], XL[8 * 64];
  __shared__ float MU[16], RS[16];

  // stage ce tile -> h (transpose)
  {
    int ch = tid >> 1, hf = tid & 1;
    const float* src = ce + ((size_t)(b * CEE + ch)) * TCC + tc0 + hf * 8;
    float4 v0 = *(const float4*)src;
    float4 v1 = *(const float4*)(src + 4);
    float vv[8] = {v0.x, v0.y, v0.z, v0.w, v1.x, v1.y, v1.z, v1.w};
    #pragma unroll
    for (int j = 0; j < 8; ++j) h[(hf * 8 + j) * 137 + ch] = vv[j];
  }
  __syncthreads();
  pack_frags(h, XH, XL, MU, RS, nullptr, nullptr, false, tid);
  __syncthreads();

  const float* Bp[3] = {b0, b1, b2};
  const float* Gp[3] = {g0, g1, g2};
  const float* Ep[3] = {e0, e1, e2};

  for (int L = 0; L < 3; ++L) {
    const int ct0 = 2 * wv, ct1 = 2 * wv + 1;
    float bb0 = Bp[L][ct0 * 16 + l16], bb1 = Bp[L][ct1 * 16 + l16];
    f32x4_t ac0, ac1;
    ac0[0] = bb0; ac0[1] = bb0; ac0[2] = bb0; ac0[3] = bb0;
    ac1[0] = bb1; ac1[1] = bb1; ac1[2] = bb1; ac1[3] = bb1;
    const uint4* wf = (const uint4*)(ws + OFF_WF) + (size_t)L * 4096;
    #pragma unroll
    for (int kt = 0; kt < 8; ++kt) {
      H4 ah, al;
      ah.u = XH[kt * 64 + lane];
      al.u = XL[kt * 64 + lane];
      uint4 q0 = wf[(kt * 8 + ct0) * 64 + lane];
      uint4 q1 = wf[(kt * 8 + ct1) * 64 + lane];
      H4 bh0, bl0, bh1, bl1;
      bh0.u.x = q0.x; bh0.u.y = q0.y; bl0.u.x = q0.z; bl0.u.y = q0.w;
      bh1.u.x = q1.x; bh1.u.y = q1.y; bl1.u.x = q1.z; bl1.u.y = q1.w;
      ac0 = __builtin_amdgcn_mfma_f32_16x16x16f16(ah.h4, bl0.h4, ac0, 0, 0, 0);
      ac0 = __builtin_amdgcn_mfma_f32_16x16x16f16(al.h4, bh0.h4, ac0, 0, 0, 0);
      ac0 = __builtin_amdgcn_mfma_f32_16x16x16f16(ah.h4, bh0.h4, ac0, 0, 0, 0);
      ac1 = __builtin_amdgcn_mfma_f32_16x16x16f16(ah.h4, bl1.h4, ac1, 0, 0, 0);
      ac1 = __builtin_amdgcn_mfma_f32_16x16x16f16(al.h4, bh1.h4, ac1, 0, 0, 0);
      ac1 = __builtin_amdgcn_mfma_f32_16x16x16f16(ah.h4, bh1.h4, ac1, 0, 0, 0);
    }
    // D -> h: row(pos) = quad*4+r, col(ch) = ct*16+l16
    #pragma unroll
    for (int r = 0; r < 4; ++r) {
      h[(quad * 4 + r) * 137 + ct0 * 16 + l16] = ac0[r];
      h[(quad * 4 + r) * 137 + ct1 * 16 + l16] = ac1[r];
    }
    __syncthreads();
    // LN stats: 16 threads per pos
    {
      int p = tid >> 4, sb = tid & 15;
      float s = 0.f, q = 0.f;
      #pragma unroll
      for (int j = 0; j < 8; ++j) {
        float v = h[p * 137 + sb + 16 * j];
        s += v; q += v * v;
      }
      #pragma unroll
      for (int m2 = 1; m2 < 16; m2 <<= 1) {
        s += __shfl_xor(s, m2, 64);
        q += __shfl_xor(q, m2, 64);
      }
      if (sb == 0) {
        float mu = s * (1.0f / CEE);
        MU[p] = mu;
        RS[p] = rsqrtf(q * (1.0f / CEE) - mu * mu + 1e-5f);
      }
    }
    __syncthreads();
    pack_frags(h, XH, XL, MU, RS, Gp[L], Ep[L], true, tid);
    __syncthreads();
  }

  // final layer CE -> 256: wave handles ct = wv*4 .. wv*4+3
  {
    const uint4* wf = (const uint4*)(ws + OFF_W3F);
    f32x4_t ac[4];
    #pragma unroll
    for (int c = 0; c < 4; ++c) {
      float bb = b3[(wv * 4 + c) * 16 + l16];
      ac[c][0] = bb; ac[c][1] = bb; ac[c][2] = bb; ac[c][3] = bb;
    }
    #pragma unroll
    for (int kt = 0; kt < 8; ++kt) {
      H4 ah, al;
      ah.u = XH[kt * 64 + lane];
      al.u = XL[kt * 64 + lane];
      #pragma unroll
      for (int c = 0; c < 4; ++c) {
        uint4 q = wf[(kt * 16 + wv * 4 + c) * 64 + lane];
        H4 bh, bl;
        bh.u.x = q.x; bh.u.y = q.y; bl.u.x = q.z; bl.u.y = q.w;
        ac[c] = __builtin_amdgcn_mfma_f32_16x16x16f16(ah.h4, bl.h4, ac[c], 0, 0, 0);
        ac[c] = __builtin_amdgcn_mfma_f32_16x16x16f16(al.h4, bh.h4, ac[c], 0, 0, 0);
        ac[c] = __builtin_amdgcn_mfma_f32_16x16x16f16(ah.h4, bh.h4, ac[c], 0, 0, 0);
      }
    }
    #pragma unroll
    for (int c = 0; c < 4; ++c)
      #pragma unroll
      for (int r = 0; r < 4; ++r)
        h2[(quad * 4 + r) * 265 + (wv * 4 + c) * 16 + l16] = ac[c][r];
  }
  __syncthreads();

  // film write: thread = ch (256), 16 contiguous tc
  {
    int ch = tid;
    float vv[16];
    #pragma unroll
    for (int t = 0; t < 16; ++t) vv[t] = h2[t * 265 + ch];
    float* dst = ws + OFF_FILM + ((size_t)(b * 256 + ch)) * TCC + tc0;
    *(float4*)(dst) = make_float4(vv[0], vv[1], vv[2], vv[3]);
    *(float4*)(dst + 4) = make_float4(vv[4], vv[5], vv[6], vv[7]);
    *(float4*)(dst + 8) = make_float4(vv[8], vv[9], vv[10], vv[11]);
    *(float4*)(dst + 12) = make_float4(vv[12], vv[13], vv[14], vv[15]);
  }
  // S epilogue: S[b][tc] = sum_n mixw[n] * beta_n (ch 192..255)
  if (wv == 0) {
    float mw = mixw[lane];
    for (int t = 0; t < 16; ++t) {
      float v = h2[t * 265 + 192 + lane] * mw;
      #pragma unroll
      for (int m2 = 1; m2 < 64; m2 <<= 1) v += __shfl_xor(v, m2, 64);
      if (lane == 0) ws[OFF_SB + b * TCC + tc0 + t] = v;
    }
  }
}

// ---------------- kernel 2: FiLM + dual-MFMA waveshaper -> partials --------
// grid: 256 t-tiles x 4 batches x 4 channel-quarters; block 256 (4 waves)
__global__ __launch_bounds__(256, 8) void k_shape(
    const float* __restrict__ exciter,
    const float* __restrict__ ws,
    const float* __restrict__ mixw,
    float* __restrict__ part) {
  const int tid = threadIdx.x;
  const int lane = tid & 63;
  const int wv = tid >> 6;
  const int bx = blockIdx.x;
  const int blk = bx & 255;
  const int b = (bx >> 8) & 3;
  const int quarter = bx >> 10;
  const int n0 = quarter * 16;
  const int t0_blk = blk * 256;
  const int tcbase = blk * 4 - 1;

  __shared__ __align__(16) float FLp[16 * 48];    // [n][j 0..5][8]: gv,gd,bv,bd,nv,nd,-,-
  __shared__ float Spair[12];
  __shared__ __align__(16) float W0s[16 * 16], B0s[16 * 16], B1s[16 * 16];
  __shared__ float B2s[16];

  if (tid < 16 * 16) {
    W0s[tid] = ws[OFF_W0S + n0 * 16 + tid];
    B0s[tid] = ws[OFF_B0S + n0 * 16 + tid];
    B1s[tid] = ws[OFF_B1S + n0 * 16 + tid];
  }
  if (tid < 16) B2s[tid] = ws[OFF_B2S + n0 + tid];
  if (tid < 96) {
    int n = tid / 6, j = tid - n * 6;
    int tc = tcbase + j; tc = tc < 0 ? 0 : (tc > 1023 ? 1023 : tc);
    int tcn = tcbase + j + 1; tcn = tcn < 0 ? 0 : (tcn > 1023 ? 1023 : tcn);
    const float* fb = ws + OFF_FILM + ((size_t)(b * 256 + n0 + n)) * TCC;
    float g_v = fb[tc], g_n = fb[tcn];
    float b_v = fb[64 * TCC + tc], b_n = fb[64 * TCC + tcn];
    float n_v = fb[128 * TCC + tc], n_n = fb[128 * TCC + tcn];
    float mwn = mixw[n0 + n];
    float* d = FLp + n * 48 + j * 8;
    d[0] = g_v; d[1] = g_n - g_v;
    d[2] = b_v; d[3] = b_n - b_v;
    d[4] = n_v * mwn; d[5] = (n_n - n_v) * mwn;
  }
  if (tid >= 96 && tid < 102 && quarter == 0) {
    int j = tid - 96;
    int tc = tcbase + j; tc = tc < 0 ? 0 : (tc > 1023 ? 1023 : tc);
    int tcn = tcbase + j + 1; tcn = tcn < 0 ? 0 : (tcn > 1023 ? 1023 : tcn);
    float s0 = ws[OFF_SB + b * TCC + tc];
    float s1 = ws[OFF_SB + b * TCC + tcn];
    Spair[2 * j] = s0; Spair[2 * j + 1] = s1 - s0;
  }
  __syncthreads();

  const int t_own = t0_blk + wv * 64 + lane;
  float pos = ((float)t_own + 0.5f) * (1.0f / 64.0f) - 0.5f;
  pos = fminf(fmaxf(pos, 0.0f), 1023.0f);
  float fi = floorf(pos);
  int i0 = (int)fi;
  const float frac = pos - fi;
  const int j0 = i0 - tcbase;        // in [0,4]

  const int quad = lane >> 4;
  const int l16 = lane & 15;

  float acc = 0.0f;
  const float* excp = exciter + ((size_t)(b * NWS + n0)) * TT + t_own;
  const uint4* afp = (const uint4*)(ws + OFF_AFRAG) + (size_t)n0 * 64 + lane;

  f32x4_t czero; czero[0] = 0.f; czero[1] = 0.f; czero[2] = 0.f; czero[3] = 0.f;

  float ev = excp[0];
  uint4 af = afp[0];
  for (int n = 0; n < 16; ++n) {
    float ev_n = 0.f; uint4 af_n = af;
    if (n < 15) {
      ev_n = excp[(size_t)(n + 1) * TT];
      af_n = afp[(n + 1) * 64];
    }
    const float* fp = FLp + n * 48 + j0 * 8;
    float4 gb = *(const float4*)(fp);
    float2 np = *(const float2*)(fp + 4);
    float gi = fmaf(gb.y, frac, gb.x);
    float bi = fmaf(gb.w, frac, gb.z);
    float gnp = fmaf(np.y, frac, np.x);
    float x = fmaf(gi, ev, bi);

    f32x4_t w0f = *(const f32x4_t*)(W0s + n * 16 + quad * 4);
    f32x4_t b0f = *(const f32x4_t*)(B0s + n * 16 + quad * 4);
    f32x4_t b1f = *(const f32x4_t*)(B1s + n * 16 + quad * 4);
    float b2v = B2s[n];
    H4 a1, a2;
    a1.u.x = af.x; a1.u.y = af.y;
    a2.u.x = af.z; a2.u.y = af.w;

    float yown = 0.0f;
    #pragma unroll
    for (int g = 0; g < 4; ++g) {
      float xg = __shfl(x, g * 16 + l16, 64);
      float s0 = sinrev(fmaf(xg, w0f[0], b0f[0]));
      float s1 = sinrev(fmaf(xg, w0f[1], b0f[1]));
      float s2 = sinrev(fmaf(xg, w0f[2], b0f[2]));
      float s3 = sinrev(fmaf(xg, w0f[3], b0f[3]));
      H4 bf1;
      bf1.f2[0] = __builtin_amdgcn_cvt_pkrtz(s0, s1);
      bf1.f2[1] = __builtin_amdgcn_cvt_pkrtz(s2, s3);
      f32x4_t d1 = __builtin_amdgcn_mfma_f32_16x16x16f16(a1.h4, bf1.h4, b1f, 0, 0, 0);
      float u0 = sinrev(d1[0]);
      float u1 = sinrev(d1[1]);
      float u2 = sinrev(d1[2]);
      float u3 = sinrev(d1[3]);
      H4 bf2;
      bf2.f2[0] = __builtin_amdgcn_cvt_pkrtz(u0, u1);
      bf2.f2[1] = __builtin_amdgcn_cvt_pkrtz(u2, u3);
      f32x4_t d2 = __builtin_amdgcn_mfma_f32_16x16x16f16(a2.h4, bf2.h4, czero, 0, 0, 0);
      yown = (quad == g) ? d2[0] : yown;   // all D2 rows equal; pick own group
    }
    float z = sinrev(yown + b2v);
    acc = fmaf(gnp, z, acc);
    ev = ev_n; af = af_n;
  }
  if (quarter == 0) {
    float2 sp = *(const float2*)(Spair + 2 * j0);
    acc += fmaf(sp.y, frac, sp.x);
  }
  part[((size_t)(quarter * NB + b)) * TT + t_own] = acc;
}

// ---------------- kernel 3: combine partials, x4 repeat, mixer bias --------
__global__ __launch_bounds__(256) void k_mix(
    const float* __restrict__ part,
    const float* __restrict__ mixb,
    float* __restrict__ out) {
  int idx = blockIdx.x * 256 + threadIdx.x;   // over B*T/4
  float m = mixb[0];
  float4 a = ((const float4*)part)[idx];
  float4 c = ((const float4*)(part + (size_t)NB * TT))[idx];
  float4 d = ((const float4*)(part + (size_t)2 * NB * TT))[idx];
  float4 e = ((const float4*)(part + (size_t)3 * NB * TT))[idx];
  float4* o = (float4*)(out + (size_t)idx * 16);
  float s0 = a.x + c.x + d.x + e.x + m;
  float s1 = a.y + c.y + d.y + e.y + m;
  float s2 = a.z + c.z + d.z + e.z + m;
  float s3 = a.w + c.w + d.w + e.w + m;
  o[0] = make_float4(s0, s0, s0, s0);
  o[1] = make_float4(s1, s1, s1, s1);
  o[2] = make_float4(s2, s2, s2, s2);
  o[3] = make_float4(s3, s3, s3, s3);
}

extern "C" void kernel_launch(void* const* d_in, const int* in_sizes, int n_in,
                              void* d_out, int out_size, void* d_ws, size_t ws_size,
                              hipStream_t stream) {
  const float* exciter = (const float*)d_in[0];
  const float* ce      = (const float*)d_in[1];
  const float* w0  = (const float*)d_in[2];
  const float* b0  = (const float*)d_in[3];
  const float* g0  = (const float*)d_in[4];
  const float* e0  = (const float*)d_in[5];
  const float* w1  = (const float*)d_in[6];
  const float* b1  = (const float*)d_in[7];
  const float* g1  = (const float*)d_in[8];
  const float* e1  = (const float*)d_in[9];
  const float* w2  = (const float*)d_in[10];
  const float* b2  = (const float*)d_in[11];
  const float* g2  = (const float*)d_in[12];
  const float* e2  = (const float*)d_in[13];
  const float* w3  = (const float*)d_in[14];
  const float* b3  = (const float*)d_in[15];
  const float* iscale = (const float*)d_in[16];
  const float* sw0 = (const float*)d_in[17];
  const float* sb0 = (const float*)d_in[18];
  const float* sw1 = (const float*)d_in[19];
  const float* sb1 = (const float*)d_in[20];
  const float* sw2 = (const float*)d_in[21];
  const float* sb2 = (const float*)d_in[22];
  const float* mixw = (const float*)d_in[23];
  const float* mixb = (const float*)d_in[24];

  float* ws = (float*)d_ws;

  hipLaunchKernelGGL(k_prep, dim3(96), dim3(256), 0, stream,
                     iscale, sw0, sb0, sw1, sb1, sw2, sb2, w0, w1, w2, w3, ws);
  hipLaunchKernelGGL(k_mlp, dim3(256), dim3(256), 0, stream,
                     ce, b0, g0, e0, b1, g1, e1, b2, g2, e2, b3, mixw, ws);
  hipLaunchKernelGGL(k_shape, dim3(4096), dim3(256), 0, stream,
                     exciter, ws, mixw, ws + OFF_PART);
  hipLaunchKernelGGL(k_mix, dim3(256), dim3(256), 0, stream,
                     ws + OFF_PART, mixb, (float*)d_out);
}